// Round 11
// baseline (279.189 us; speedup 1.0000x reference)
//
#include <hip/hip_runtime.h>
#include <hip/hip_fp16.h>

#define N_USERS 50000
#define N_ITEMS 75000
#define N_NODES 125000
#define N_PAD   125008               // padded to multiple of 16 for MFMA tiles
#define NNZ     1250000
#define EMB     64
#define N_LAYERS 3
#define BATCH   4096
#define CONCAT  256

#define CHUNK   4096                          // edges per scatter block
#define NCHUNK  ((NNZ + CHUNK - 1) / CHUNK)   // 306
#define ROW_CAP 64                            // max degree (Poisson-10: P(>=64)~0)
#define FB_NODES 64                           // nodes per fused-layer block (4 waves)
#define NBLK    ((N_NODES + FB_NODES - 1) / FB_NODES)  // 1954 blocks
#define SCAP    8                             // max samples per node (mean ~0.1)
#define NACT_BLK ((3 * BATCH + FB_NODES - 1) / FB_NODES)  // 192 blocks (last layer)

// init work decomposition (4-float chunks)
#define F4      (N_NODES * EMB / 4)           // 2,000,000 f16-convert chunks
#define G4      (3 * BATCH * EMB / 4)         // 196,608 gather0 chunks
#define SM      (3 * BATCH)                   // 12,288 sample-map entries
#define INIT_ITEMS (F4 + G4 + SM)
#define INIT_BLOCKS ((INIT_ITEMS + 255) / 256)

typedef _Float16 half8  __attribute__((ext_vector_type(8)));
typedef _Float16 half4  __attribute__((ext_vector_type(4)));
typedef float    floatx4 __attribute__((ext_vector_type(4)));

// 'user' may be int64 (jax x64) or int32. Detect from data.
__device__ __forceinline__ bool user_is_i64(const void* uptr) {
    const int* u = (const int*)uptr;
    return (u[1] | u[3] | u[5] | u[7]) == 0;
}
__device__ __forceinline__ int load_user(const void* uptr, int b, bool is64) {
    return is64 ? (int)((const long long*)uptr)[b] : ((const int*)uptr)[b];
}
__device__ __forceinline__ int sample_node(const void* user, const int* pos,
                                           const int* neg, int which, int b,
                                           bool is64) {
    if (which == 0) return load_user(user, b, is64);
    return N_USERS + (which == 1 ? pos[b] : neg[b]);
}

// se word (4B): (fp16bits << 17) | col ;  word 0 => col 0, val +0.0
__device__ __forceinline__ float unpack_val(unsigned w) {
    unsigned short us = (unsigned short)(w >> 17);
    _Float16 h = __builtin_bit_cast(_Float16, us);
    return (float)h;
}

// ---------------------------------------------------------------------------
// Fused CSR-scatter + init. Uniform branch on blockIdx.x:
//   blocks [0, NCHUNK): direct-scatter edges into fixed-cap row-major se
//                       (se[row*64 + atomic pos]); no staging, no sort pass.
//   blocks [NCHUNK, ..): vectorized f16 convert + gather0 + sample-map build
//                        (+ active-node list: nodes with >=1 sample)
// ---------------------------------------------------------------------------
__global__ __launch_bounds__(256) void part_init_kernel(
    const int* __restrict__ row, const int* __restrict__ col,
    const float* __restrict__ vals, const float* __restrict__ emb,
    const void* __restrict__ user, const int* __restrict__ pos,
    const int* __restrict__ neg,
    _Float16* __restrict__ f16, float* __restrict__ out,
    int* __restrict__ rowcnt, int* __restrict__ scnt, int* __restrict__ smap,
    int* __restrict__ nact, int* __restrict__ active,
    unsigned* __restrict__ se) {

    if (blockIdx.x < NCHUNK) {
        // ---- direct edge scatter ----
        int t = threadIdx.x;
        int e0 = blockIdx.x * CHUNK;
        int e1 = e0 + CHUNK; if (e1 > NNZ) e1 = NNZ;
        for (int e = e0 + t; e < e1; e += 256) {
            int r = row[e];
            _Float16 hv = (_Float16)vals[e];
            unsigned hb = (unsigned)__builtin_bit_cast(unsigned short, hv);
            unsigned w = (hb << 17) | (unsigned)col[e];
            int p = atomicAdd(&rowcnt[r], 1);
            if (p < ROW_CAP)
                se[(size_t)r * ROW_CAP + p] = w;
        }
    } else {
        // ---- init: f16 convert (float4), gather0 (float4), sample map ----
        int idx = (blockIdx.x - NCHUNK) * 256 + threadIdx.x;
        bool is64 = user_is_i64(user);
        if (idx < F4) {
            floatx4 v = *(const floatx4*)(emb + (size_t)idx * 4);
            half4 o;
            #pragma unroll
            for (int i = 0; i < 4; ++i) o[i] = (_Float16)v[i];
            *(half4*)(f16 + (size_t)idx * 4) = o;
        } else if (idx < F4 + G4) {
            int j = idx - F4;                 // 4-float chunk of gather0
            int which = j / (BATCH * 16);
            int rem   = j % (BATCH * 16);
            int bb = rem >> 4, c4 = rem & 15; // 16 chunks per 64-dim row
            int node = sample_node(user, pos, neg, which, bb, is64);
            floatx4 v = *(const floatx4*)(emb + (size_t)node * EMB + c4 * 4);
            *(floatx4*)(out + (size_t)(which * BATCH + bb) * CONCAT + c4 * 4) = v;
        } else if (idx < F4 + G4 + SM) {
            int g2 = idx - F4 - G4;
            int which = g2 / BATCH, bb = g2 % BATCH;
            int node = sample_node(user, pos, neg, which, bb, is64);
            int slot = atomicAdd(&scnt[node], 1);
            if (slot < SCAP) smap[node * SCAP + slot] = g2;
            if (slot == 0) {                  // first sample -> unique append
                int p = atomicAdd(nact, 1);
                active[p] = node;
            }
        }
    }
}

// ---------------------------------------------------------------------------
// Fused layer kernel v6 (layers 0..N-2): contiguous node order, 64 nodes per
// block, 256 threads. Gather: 2 passes x 8 nodes/wave, 8 lanes/node, 8
// dims/lane, 16B row loads, 8-deep edge batch, se-prefetch pipeline.
// Row-major fixed-cap CSR: j = node*ROW_CAP, end = j + rowcnt[node].
// Dense: all 4 waves run a 16-node MFMA tile; fused epilogue.
// ---------------------------------------------------------------------------
__global__ __launch_bounds__(256) void layer_kernel(
    const int* __restrict__ rowcnt, const unsigned* __restrict__ se,
    const _Float16* __restrict__ fin, _Float16* __restrict__ fout,
    const float* __restrict__ W1, const float* __restrict__ b1,
    const float* __restrict__ W2, const float* __restrict__ b2,
    const int* __restrict__ scnt, const int* __restrict__ smap,
    float* __restrict__ out, int layer) {

    // wlds[m][n][*]: 16B chunk c16 of row n stored at chunk (c16 ^ (n&7))
    __shared__ _Float16 wlds[2][EMB][EMB];
    __shared__ _Float16 alds[FB_NODES][EMB];  // same swizzle on chunk index

    int tid = threadIdx.x;

    // --- stage weights (f32 -> f16, swizzled): 2 chunks/thread/matrix ---
    {
        const float* Wsrc0 = W1 + layer * EMB * EMB;
        const float* Wsrc1 = W2 + layer * EMB * EMB;
        #pragma unroll
        for (int m = 0; m < 2; ++m) {
            const float* Ws = m ? Wsrc1 : Wsrc0;
            for (int c = tid; c < 512; c += 256) {   // 64 rows x 8 chunks
                int n = c >> 3, c16 = c & 7;
                const float* p = Ws + n * EMB + c16 * 8;
                floatx4 wa = *(const floatx4*)p, wb = *(const floatx4*)(p + 4);
                half8 h;
                #pragma unroll
                for (int i = 0; i < 4; ++i) {
                    h[i] = (_Float16)wa[i]; h[4 + i] = (_Float16)wb[i];
                }
                *(half8*)(&wlds[m][n][(c16 ^ (n & 7)) * 8]) = h;
            }
        }
    }

    int wave = tid >> 6, lane = tid & 63;
    int g = lane >> 3;                 // node subgroup 0..7
    int k = lane & 7;                  // dim block: dims [8k, 8k+8)
    int base = blockIdx.x * FB_NODES;
    const _Float16* fink = fin + k * 8;

    // --- gather: two passes of 8 nodes per wave, pipelined se prefetch ---
    for (int p = 0; p < 2; ++p) {
        int ln = p * 32 + wave * 8 + g;    // local node 0..63
        int node = base + ln;
        bool valid = node < N_NODES;
        int cnt = valid ? rowcnt[node] : 0;
        if (cnt > ROW_CAP) cnt = ROW_CAP;
        int j   = node * ROW_CAP;
        int end = j + cnt;

        float acc[8] = {0.f, 0.f, 0.f, 0.f, 0.f, 0.f, 0.f, 0.f};
        unsigned ev[8];
        #pragma unroll
        for (int t = 0; t < 8; ++t)
            ev[t] = (j + t < end) ? se[j + t] : 0u;   // 0 => col 0, +0.0

        while (__any(j < end)) {
            int jn = j + 8;
            half8 h[8];
            #pragma unroll
            for (int t = 0; t < 8; ++t) {
                int c = (int)(ev[t] & 0x1FFFFu);
                h[t] = *(const half8*)(fink + (size_t)c * EMB);
            }
            unsigned evn[8];
            #pragma unroll
            for (int t = 0; t < 8; ++t)
                evn[t] = (jn + t < end) ? se[jn + t] : 0u;
            #pragma unroll
            for (int t = 0; t < 8; ++t) {
                float val = unpack_val(ev[t]);
                #pragma unroll
                for (int i = 0; i < 8; ++i)
                    acc[i] += (float)h[t][i] * val;   // v_fma_mix_f32
                ev[t] = evn[t];
            }
            j = jn;
        }
        half8 o;
        #pragma unroll
        for (int i = 0; i < 8; ++i) o[i] = (_Float16)acc[i];
        *(half8*)(&alds[ln][(k ^ (ln & 7)) * 8]) = o;
    }
    __syncthreads();

    // --- dense phase: all 4 waves, each one 16-node MFMA tile ---
    {
        int lm = lane & 15, quad = lane >> 4;
        int ln0 = wave * 16 + lm;
        int nb = base + wave * 16;
        int nodeD = nb + lm;
        int sw = lm & 7;                       // (ln0 & 7) == (lm & 7)

        half8 a0 = *(const half8*)(&alds[ln0][(quad ^ sw) * 8]);
        half8 a1 = *(const half8*)(&alds[ln0][((quad + 4) ^ sw) * 8]);

        int nsafe = nodeD < N_NODES ? nodeD : 0;
        const half8* fp = (const half8*)(fin + (size_t)nsafe * EMB + quad * 8);
        half8 f0 = fp[0], f1 = fp[4];
        half8 g0 = a0 * f0, g1 = a1 * f1;

        float nfv[4][4];
        float sq[4] = {0.f, 0.f, 0.f, 0.f};

        #pragma unroll
        for (int t = 0; t < 4; ++t) {
            int n = t * 16 + lm;
            float bias1 = b1[layer * EMB + n];
            float bias2 = b2[layer * EMB + n];
            half8 w10 = *(const half8*)(&wlds[0][n][(quad ^ sw) * 8]);
            half8 w11 = *(const half8*)(&wlds[0][n][((quad + 4) ^ sw) * 8]);
            half8 w20 = *(const half8*)(&wlds[1][n][(quad ^ sw) * 8]);
            half8 w21 = *(const half8*)(&wlds[1][n][((quad + 4) ^ sw) * 8]);
            floatx4 d1 = {0.f, 0.f, 0.f, 0.f}, d2 = {0.f, 0.f, 0.f, 0.f};
            d1 = __builtin_amdgcn_mfma_f32_16x16x32_f16(a0, w10, d1, 0, 0, 0);
            d1 = __builtin_amdgcn_mfma_f32_16x16x32_f16(a1, w11, d1, 0, 0, 0);
            d2 = __builtin_amdgcn_mfma_f32_16x16x32_f16(g0, w20, d2, 0, 0, 0);
            d2 = __builtin_amdgcn_mfma_f32_16x16x32_f16(g1, w21, d2, 0, 0, 0);
            #pragma unroll
            for (int r = 0; r < 4; ++r) {
                float p1v = d1[r] + bias1;
                p1v = p1v > 0.f ? p1v : 0.2f * p1v;
                float p2v = d2[r] + bias2;
                p2v = p2v > 0.f ? p2v : 0.2f * p2v;
                float nf = p1v + p2v;
                nfv[t][r] = nf;
                sq[r] += nf * nf;
            }
        }

        // fout store — coalesced: contiguous nodes
        #pragma unroll
        for (int t = 0; t < 4; ++t) {
            int dim = t * 16 + lm;
            #pragma unroll
            for (int r = 0; r < 4; ++r) {
                int nodeO = nb + quad * 4 + r;
                if (nodeO < N_NODES)
                    fout[(size_t)nodeO * EMB + dim] = (_Float16)nfv[t][r];
            }
        }

        // per-node L2 norm: reduce sq[r] across the 16 lm-lanes (same quad)
        #pragma unroll
        for (int r = 0; r < 4; ++r) {
            float v = sq[r];
            #pragma unroll
            for (int m = 1; m < 16; m <<= 1) v += __shfl_xor(v, m, 64);
            sq[r] = fmaxf(sqrtf(v), 1e-12f);
        }

        // scatter normalized rows to sampled batch positions
        #pragma unroll
        for (int r = 0; r < 4; ++r) {
            int nodeO = nb + quad * 4 + r;
            if (nodeO >= N_NODES) continue;
            int c = scnt[nodeO]; c = c < SCAP ? c : SCAP;
            float inv = 1.0f / sq[r];
            for (int i2 = 0; i2 < c; ++i2) {
                int smp = smap[nodeO * SCAP + i2];
                float* po = out + (size_t)smp * CONCAT + (layer + 1) * EMB;
                #pragma unroll
                for (int t = 0; t < 4; ++t)
                    po[t * 16 + lm] = nfv[t][r] * inv;
            }
        }
    }
}

// ---------------------------------------------------------------------------
// Last-layer kernel: identical math, driven by the ACTIVE-node list
// (nodes with >=1 sample, <= 12288 unique). No fout store.
// ---------------------------------------------------------------------------
__global__ __launch_bounds__(256) void layerL_kernel(
    const int* __restrict__ rowcnt, const unsigned* __restrict__ se,
    const int* __restrict__ nactp, const int* __restrict__ active,
    const _Float16* __restrict__ fin,
    const float* __restrict__ W1, const float* __restrict__ b1,
    const float* __restrict__ W2, const float* __restrict__ b2,
    const int* __restrict__ scnt, const int* __restrict__ smap,
    float* __restrict__ out, int layer) {

    __shared__ _Float16 wlds[2][EMB][EMB];
    __shared__ _Float16 alds[FB_NODES][EMB];

    int tid = threadIdx.x;
    int nact = *nactp;

    // --- stage weights (f32 -> f16, swizzled) ---
    {
        const float* Wsrc0 = W1 + layer * EMB * EMB;
        const float* Wsrc1 = W2 + layer * EMB * EMB;
        #pragma unroll
        for (int m = 0; m < 2; ++m) {
            const float* Ws = m ? Wsrc1 : Wsrc0;
            for (int c = tid; c < 512; c += 256) {
                int n = c >> 3, c16 = c & 7;
                const float* p = Ws + n * EMB + c16 * 8;
                floatx4 wa = *(const floatx4*)p, wb = *(const floatx4*)(p + 4);
                half8 h;
                #pragma unroll
                for (int i = 0; i < 4; ++i) {
                    h[i] = (_Float16)wa[i]; h[4 + i] = (_Float16)wb[i];
                }
                *(half8*)(&wlds[m][n][(c16 ^ (n & 7)) * 8]) = h;
            }
        }
    }

    int wave = tid >> 6, lane = tid & 63;
    int g = lane >> 3;
    int k = lane & 7;
    int base = blockIdx.x * FB_NODES;
    const _Float16* fink = fin + k * 8;

    // --- gather over active nodes ---
    for (int p = 0; p < 2; ++p) {
        int ln = p * 32 + wave * 8 + g;
        int idx = base + ln;
        bool valid = idx < nact;
        int node = valid ? active[idx] : 0;
        int cnt = valid ? rowcnt[node] : 0;
        if (cnt > ROW_CAP) cnt = ROW_CAP;
        int j   = node * ROW_CAP;
        int end = j + cnt;

        float acc[8] = {0.f, 0.f, 0.f, 0.f, 0.f, 0.f, 0.f, 0.f};
        unsigned ev[8];
        #pragma unroll
        for (int t = 0; t < 8; ++t)
            ev[t] = (j + t < end) ? se[j + t] : 0u;

        while (__any(j < end)) {
            int jn = j + 8;
            half8 h[8];
            #pragma unroll
            for (int t = 0; t < 8; ++t) {
                int c = (int)(ev[t] & 0x1FFFFu);
                h[t] = *(const half8*)(fink + (size_t)c * EMB);
            }
            unsigned evn[8];
            #pragma unroll
            for (int t = 0; t < 8; ++t)
                evn[t] = (jn + t < end) ? se[jn + t] : 0u;
            #pragma unroll
            for (int t = 0; t < 8; ++t) {
                float val = unpack_val(ev[t]);
                #pragma unroll
                for (int i = 0; i < 8; ++i)
                    acc[i] += (float)h[t][i] * val;
                ev[t] = evn[t];
            }
            j = jn;
        }
        half8 o;
        #pragma unroll
        for (int i = 0; i < 8; ++i) o[i] = (_Float16)acc[i];
        *(half8*)(&alds[ln][(k ^ (ln & 7)) * 8]) = o;
    }
    __syncthreads();

    // --- dense phase (active nodes, gathered fin, no fout store) ---
    {
        int lm = lane & 15, quad = lane >> 4;
        int ln0 = wave * 16 + lm;
        int idxD = base + ln0;
        int nodeD = (idxD < nact) ? active[idxD] : -1;
        int sw = lm & 7;

        half8 a0 = *(const half8*)(&alds[ln0][(quad ^ sw) * 8]);
        half8 a1 = *(const half8*)(&alds[ln0][((quad + 4) ^ sw) * 8]);

        int nsafe = nodeD >= 0 ? nodeD : 0;
        const half8* fp = (const half8*)(fin + (size_t)nsafe * EMB + quad * 8);
        half8 f0 = fp[0], f1 = fp[4];
        half8 g0 = a0 * f0, g1 = a1 * f1;

        float nfv[4][4];
        float sq[4] = {0.f, 0.f, 0.f, 0.f};

        #pragma unroll
        for (int t = 0; t < 4; ++t) {
            int n = t * 16 + lm;
            float bias1 = b1[layer * EMB + n];
            float bias2 = b2[layer * EMB + n];
            half8 w10 = *(const half8*)(&wlds[0][n][(quad ^ sw) * 8]);
            half8 w11 = *(const half8*)(&wlds[0][n][((quad + 4) ^ sw) * 8]);
            half8 w20 = *(const half8*)(&wlds[1][n][(quad ^ sw) * 8]);
            half8 w21 = *(const half8*)(&wlds[1][n][((quad + 4) ^ sw) * 8]);
            floatx4 d1 = {0.f, 0.f, 0.f, 0.f}, d2 = {0.f, 0.f, 0.f, 0.f};
            d1 = __builtin_amdgcn_mfma_f32_16x16x32_f16(a0, w10, d1, 0, 0, 0);
            d1 = __builtin_amdgcn_mfma_f32_16x16x32_f16(a1, w11, d1, 0, 0, 0);
            d2 = __builtin_amdgcn_mfma_f32_16x16x32_f16(g0, w20, d2, 0, 0, 0);
            d2 = __builtin_amdgcn_mfma_f32_16x16x32_f16(g1, w21, d2, 0, 0, 0);
            #pragma unroll
            for (int r = 0; r < 4; ++r) {
                float p1v = d1[r] + bias1;
                p1v = p1v > 0.f ? p1v : 0.2f * p1v;
                float p2v = d2[r] + bias2;
                p2v = p2v > 0.f ? p2v : 0.2f * p2v;
                float nf = p1v + p2v;
                nfv[t][r] = nf;
                sq[r] += nf * nf;
            }
        }

        int nodeO[4];
        #pragma unroll
        for (int r = 0; r < 4; ++r)
            nodeO[r] = __shfl(nodeD, quad * 4 + r, 64);

        #pragma unroll
        for (int r = 0; r < 4; ++r) {
            float v = sq[r];
            #pragma unroll
            for (int m = 1; m < 16; m <<= 1) v += __shfl_xor(v, m, 64);
            sq[r] = fmaxf(sqrtf(v), 1e-12f);
        }

        #pragma unroll
        for (int r = 0; r < 4; ++r) {
            if (nodeO[r] < 0) continue;
            int c = scnt[nodeO[r]]; c = c < SCAP ? c : SCAP;
            float inv = 1.0f / sq[r];
            for (int i2 = 0; i2 < c; ++i2) {
                int smp = smap[nodeO[r] * SCAP + i2];
                float* po = out + (size_t)smp * CONCAT + (layer + 1) * EMB;
                #pragma unroll
                for (int t = 0; t < 4; ++t)
                    po[t * 16 + lm] = nfv[t][r] * inv;
            }
        }
    }
}

extern "C" void kernel_launch(void* const* d_in, const int* in_sizes, int n_in,
                              void* d_out, int out_size, void* d_ws, size_t ws_size,
                              hipStream_t stream) {
    const void* user = d_in[0];
    const int* pos  = (const int*)d_in[1];
    const int* neg  = (const int*)d_in[2];
    const int* row  = (const int*)d_in[3];
    const int* col  = (const int*)d_in[4];
    const float* vals = (const float*)d_in[5];
    const float* emb  = (const float*)d_in[6];
    const float* W1   = (const float*)d_in[7];
    const float* b1   = (const float*)d_in[8];
    const float* W2   = (const float*)d_in[9];
    const float* b2   = (const float*)d_in[10];

    // ws layout (all offsets 8B-aligned):
    _Float16* f16a   = (_Float16*)d_ws;                       // 16 MB
    _Float16* f16b   = f16a + (size_t)N_PAD * EMB;            // 16 MB
    // zero region (contiguous): rowcnt | scnt | nact
    int*      rowcnt = (int*)(f16b + (size_t)N_PAD * EMB);    // 125000 ints
    int*      scnt   = rowcnt + N_NODES;                      // 125000 ints
    int*      nact   = scnt + N_NODES;                        // 8 ints
    int*      active = nact + 8;                              // 12288 ints
    int*      smap   = active + 3 * BATCH;                    // 1,000,000 ints
    unsigned* se     = (unsigned*)(smap + N_NODES * SCAP);    // 125000*64*4 = 32 MB

    float* out = (float*)d_out;

    // zero rowcnt + scnt + nact in one memset (contiguous)
    hipMemsetAsync(rowcnt, 0, (size_t)(2 * N_NODES + 8) * sizeof(int), stream);

    // fused direct CSR-scatter + init (+gather0 +sample-map +active-list)
    part_init_kernel<<<NCHUNK + INIT_BLOCKS, 256, 0, stream>>>(
        row, col, vals, emb, user, pos, neg, f16a, out, rowcnt, scnt, smap,
        nact, active, se);

    const _Float16* fin = f16a;
    _Float16* fout = f16b;
    for (int l = 0; l < N_LAYERS - 1; ++l) {
        layer_kernel<<<NBLK, 256, 0, stream>>>(
            rowcnt, se, fin, fout, W1, b1, W2, b2, scnt, smap, out, l);
        const _Float16* tmp = fout; fout = (_Float16*)fin; fin = (const _Float16*)tmp;
    }
    layerL_kernel<<<NACT_BLK, 256, 0, stream>>>(
        rowcnt, se, nact, active, fin, W1, b1, W2, b2, scnt, smap, out,
        N_LAYERS - 1);
}

// Round 12
// 229.796 us; speedup vs baseline: 1.2149x; 1.2149x over previous
//
#include <hip/hip_runtime.h>
#include <hip/hip_fp16.h>

#define N_USERS 50000
#define N_ITEMS 75000
#define N_NODES 125000
#define N_PAD   125008               // padded to multiple of 16 for MFMA tiles
#define NNZ     1250000
#define EMB     64
#define N_LAYERS 3
#define BATCH   4096
#define CONCAT  256

#define BROWS   128                           // rows per bucket
#define NB      ((N_NODES + BROWS - 1) / BROWS)   // 977 buckets
#define CHUNK   4096                          // edges per partition block
#define NCHUNK  ((NNZ + CHUNK - 1) / CHUNK)   // 306
#define EPT     (CHUNK / 256)                 // 16 edges per thread
#define BCAP    1600                          // bucket capacity (mean 1280, +9 sigma)
#define FB_NODES 64                           // nodes per fused-layer block (4 waves)
#define NBLK    ((N_NODES + FB_NODES - 1) / FB_NODES)  // 1954 blocks
#define SCAP    8                             // max samples per node (mean ~0.1)
#define NACT_BLK ((3 * BATCH + FB_NODES - 1) / FB_NODES)  // 192 blocks (last layer)

// init work decomposition (4-float chunks)
#define F4      (N_NODES * EMB / 4)           // 2,000,000 f16-convert chunks
#define G4      (3 * BATCH * EMB / 4)         // 196,608 gather0 chunks
#define SM      (3 * BATCH)                   // 12,288 sample-map entries
#define INIT_ITEMS (F4 + G4 + SM)
#define INIT_BLOCKS ((INIT_ITEMS + 255) / 256)

typedef _Float16 half8  __attribute__((ext_vector_type(8)));
typedef _Float16 half4  __attribute__((ext_vector_type(4)));
typedef float    floatx4 __attribute__((ext_vector_type(4)));

// 'user' may be int64 (jax x64) or int32. Detect from data.
__device__ __forceinline__ bool user_is_i64(const void* uptr) {
    const int* u = (const int*)uptr;
    return (u[1] | u[3] | u[5] | u[7]) == 0;
}
__device__ __forceinline__ int load_user(const void* uptr, int b, bool is64) {
    return is64 ? (int)((const long long*)uptr)[b] : ((const int*)uptr)[b];
}
__device__ __forceinline__ int sample_node(const void* user, const int* pos,
                                           const int* neg, int which, int b,
                                           bool is64) {
    if (which == 0) return load_user(user, b, is64);
    return N_USERS + (which == 1 ? pos[b] : neg[b]);
}

// staged record (8B): [24..37] fp16(val) | [17..23] row&127 | [0..16] col
// final se word (4B): (fp16bits << 17) | col ;  word 0 => col 0, val +0.0
__device__ __forceinline__ float unpack_val(unsigned w) {
    unsigned short us = (unsigned short)(w >> 17);
    _Float16 h = __builtin_bit_cast(_Float16, us);
    return (float)h;
}

// ---------------------------------------------------------------------------
// Fused partition + init. Uniform branch on blockIdx.x:
//   blocks [0, NCHUNK): edge partition into fixed-cap buckets (LDS-staged —
//   round-11 lesson: direct 4B scatter costs 65 µs in write-allocate traffic)
//   blocks [NCHUNK, ..): vectorized f16 convert + gather0 + sample-map build
//                        (+ active-node list: nodes with >=1 sample)
// ---------------------------------------------------------------------------
__global__ __launch_bounds__(256) void part_init_kernel(
    const int* __restrict__ row, const int* __restrict__ col,
    const float* __restrict__ vals, const float* __restrict__ emb,
    const void* __restrict__ user, const int* __restrict__ pos,
    const int* __restrict__ neg,
    _Float16* __restrict__ f16, float* __restrict__ out,
    int* __restrict__ bcnt, int* __restrict__ scnt, int* __restrict__ smap,
    int* __restrict__ nact, int* __restrict__ active,
    unsigned long long* __restrict__ sw8) {

    __shared__ int h[NB];
    __shared__ int base[NB];

    if (blockIdx.x < NCHUNK) {
        // ---- edge partition ----
        int t = threadIdx.x;
        int e0 = blockIdx.x * CHUNK;
        int e1 = e0 + CHUNK; if (e1 > NNZ) e1 = NNZ;
        for (int i = t; i < NB; i += 256) h[i] = 0;
        __syncthreads();

        unsigned long long rec[EPT];
        int bkt[EPT];
        int ps[EPT];
        int cnt = 0;
        for (int e = e0 + t; e < e1; e += 256) {
            int r = row[e];
            int b = r >> 7;
            _Float16 hv = (_Float16)vals[e];
            unsigned hb = (unsigned)__builtin_bit_cast(unsigned short, hv);
            rec[cnt] = ((unsigned long long)hb << 24)
                     | ((unsigned)(r & 127) << 17)
                     | (unsigned)col[e];
            bkt[cnt] = b;
            ps[cnt] = atomicAdd(&h[b], 1);
            ++cnt;
        }
        __syncthreads();
        for (int i = t; i < NB; i += 256) {
            int c = h[i];
            if (c) base[i] = atomicAdd(&bcnt[i], c);
        }
        __syncthreads();
        for (int k = 0; k < cnt; ++k) {
            int b = bkt[k];
            sw8[(size_t)b * BCAP + base[b] + ps[k]] = rec[k];
        }
    } else {
        // ---- init: f16 convert (float4), gather0 (float4), sample map ----
        int idx = (blockIdx.x - NCHUNK) * 256 + threadIdx.x;
        bool is64 = user_is_i64(user);
        if (idx < F4) {
            floatx4 v = *(const floatx4*)(emb + (size_t)idx * 4);
            half4 o;
            #pragma unroll
            for (int i = 0; i < 4; ++i) o[i] = (_Float16)v[i];
            *(half4*)(f16 + (size_t)idx * 4) = o;
        } else if (idx < F4 + G4) {
            int j = idx - F4;                 // 4-float chunk of gather0
            int which = j / (BATCH * 16);
            int rem   = j % (BATCH * 16);
            int bb = rem >> 4, c4 = rem & 15; // 16 chunks per 64-dim row
            int node = sample_node(user, pos, neg, which, bb, is64);
            floatx4 v = *(const floatx4*)(emb + (size_t)node * EMB + c4 * 4);
            *(floatx4*)(out + (size_t)(which * BATCH + bb) * CONCAT + c4 * 4) = v;
        } else if (idx < F4 + G4 + SM) {
            int g2 = idx - F4 - G4;
            int which = g2 / BATCH, bb = g2 % BATCH;
            int node = sample_node(user, pos, neg, which, bb, is64);
            int slot = atomicAdd(&scnt[node], 1);
            if (slot < SCAP) smap[node * SCAP + slot] = g2;
            if (slot == 0) {                  // first sample -> unique append
                int p = atomicAdd(nact, 1);
                active[p] = node;
            }
        }
    }
}

// ---------------------------------------------------------------------------
// In-bucket counting sort (one block per bucket, all LDS) -> bucket-padded
// CSR: se stays at b*BCAP + local. Per-row absolute start/end -> off/endv.
// ---------------------------------------------------------------------------
__global__ __launch_bounds__(256) void bucket_sort_kernel(
    const int* __restrict__ bcnt,
    const unsigned long long* __restrict__ sw8,
    unsigned* __restrict__ se, int* __restrict__ off, int* __restrict__ endv) {
    __shared__ unsigned long long ew[BCAP];
    __shared__ unsigned eo[BCAP];
    __shared__ int rh[BROWS], rb[BROWS], rc[BROWS];
    __shared__ int s[256];

    int b = blockIdx.x, t = threadIdx.x;
    int n = bcnt[b];
    int s0 = b * BCAP;
    if (t < BROWS) rh[t] = 0;
    __syncthreads();
    const unsigned long long* src = sw8 + (size_t)b * BCAP;
    for (int i = t; i < n; i += 256) {
        unsigned long long rec = src[i];
        ew[i] = rec;
        atomicAdd(&rh[(int)((rec >> 17) & 127)], 1);
    }
    __syncthreads();
    s[t] = (t < BROWS) ? rh[t] : 0;
    __syncthreads();
    for (int d = 1; d < 256; d <<= 1) {
        int x = (t >= d) ? s[t - d] : 0;
        __syncthreads();
        s[t] += x;
        __syncthreads();
    }
    if (t < BROWS) {
        int excl = s[t] - rh[t];
        rb[t] = excl;
        rc[t] = 0;
        int r = b * BROWS + t;
        if (r < N_NODES) {
            off[r]  = s0 + excl;
            endv[r] = s0 + s[t];
        }
    }
    __syncthreads();
    for (int i = t; i < n; i += 256) {
        unsigned long long rec = ew[i];
        int r = (int)((rec >> 17) & 127);
        int p = rb[r] + atomicAdd(&rc[r], 1);
        eo[p] = (unsigned)(((rec >> 24) << 17) | (rec & 0x1FFFFULL));
    }
    __syncthreads();
    for (int i = t; i < n; i += 256)
        se[(size_t)s0 + i] = eo[i];
}

// ---------------------------------------------------------------------------
// Fused layer kernel v5 (layers 0..N-2): contiguous node order, 64 nodes per
// block, 256 threads. Gather: 2 passes x 8 nodes/wave, 8 lanes/node, 8
// dims/lane, 16B row loads, 8-deep edge batch, se-prefetch pipeline.
// LDS 24 KB -> 6 blocks/CU. Dense: all 4 waves run a 16-node MFMA tile;
// fused epilogue (fout store + L2-norm + sample scatter).
// ---------------------------------------------------------------------------
__global__ __launch_bounds__(256) void layer_kernel(
    const int* __restrict__ off, const int* __restrict__ endv,
    const unsigned* __restrict__ se,
    const _Float16* __restrict__ fin, _Float16* __restrict__ fout,
    const float* __restrict__ W1, const float* __restrict__ b1,
    const float* __restrict__ W2, const float* __restrict__ b2,
    const int* __restrict__ scnt, const int* __restrict__ smap,
    float* __restrict__ out, int layer) {

    // wlds[m][n][*]: 16B chunk c16 of row n stored at chunk (c16 ^ (n&7))
    __shared__ _Float16 wlds[2][EMB][EMB];
    __shared__ _Float16 alds[FB_NODES][EMB];  // same swizzle on chunk index

    int tid = threadIdx.x;

    // --- stage weights (f32 -> f16, swizzled): 2 chunks/thread/matrix ---
    {
        const float* Wsrc0 = W1 + layer * EMB * EMB;
        const float* Wsrc1 = W2 + layer * EMB * EMB;
        #pragma unroll
        for (int m = 0; m < 2; ++m) {
            const float* Ws = m ? Wsrc1 : Wsrc0;
            for (int c = tid; c < 512; c += 256) {   // 64 rows x 8 chunks
                int n = c >> 3, c16 = c & 7;
                const float* p = Ws + n * EMB + c16 * 8;
                floatx4 wa = *(const floatx4*)p, wb = *(const floatx4*)(p + 4);
                half8 h;
                #pragma unroll
                for (int i = 0; i < 4; ++i) {
                    h[i] = (_Float16)wa[i]; h[4 + i] = (_Float16)wb[i];
                }
                *(half8*)(&wlds[m][n][(c16 ^ (n & 7)) * 8]) = h;
            }
        }
    }

    int wave = tid >> 6, lane = tid & 63;
    int g = lane >> 3;                 // node subgroup 0..7
    int k = lane & 7;                  // dim block: dims [8k, 8k+8)
    int base = blockIdx.x * FB_NODES;
    const _Float16* fink = fin + k * 8;

    // --- gather: two passes of 8 nodes per wave, pipelined se prefetch ---
    for (int p = 0; p < 2; ++p) {
        int ln = p * 32 + wave * 8 + g;    // local node 0..63
        int node = base + ln;
        bool valid = node < N_NODES;
        int j   = valid ? off[node]  : 0;
        int end = valid ? endv[node] : 0;

        float acc[8] = {0.f, 0.f, 0.f, 0.f, 0.f, 0.f, 0.f, 0.f};
        unsigned ev[8];
        #pragma unroll
        for (int t = 0; t < 8; ++t)
            ev[t] = (j + t < end) ? se[j + t] : 0u;   // 0 => col 0, +0.0

        while (__any(j < end)) {
            int jn = j + 8;
            half8 h[8];
            #pragma unroll
            for (int t = 0; t < 8; ++t) {
                int c = (int)(ev[t] & 0x1FFFFu);
                h[t] = *(const half8*)(fink + (size_t)c * EMB);
            }
            unsigned evn[8];
            #pragma unroll
            for (int t = 0; t < 8; ++t)
                evn[t] = (jn + t < end) ? se[jn + t] : 0u;
            #pragma unroll
            for (int t = 0; t < 8; ++t) {
                float val = unpack_val(ev[t]);
                #pragma unroll
                for (int i = 0; i < 8; ++i)
                    acc[i] += (float)h[t][i] * val;   // v_fma_mix_f32
                ev[t] = evn[t];
            }
            j = jn;
        }
        half8 o;
        #pragma unroll
        for (int i = 0; i < 8; ++i) o[i] = (_Float16)acc[i];
        *(half8*)(&alds[ln][(k ^ (ln & 7)) * 8]) = o;
    }
    __syncthreads();

    // --- dense phase: all 4 waves, each one 16-node MFMA tile ---
    {
        int lm = lane & 15, quad = lane >> 4;
        int ln0 = wave * 16 + lm;
        int nb = base + wave * 16;
        int nodeD = nb + lm;
        int sw = lm & 7;                       // (ln0 & 7) == (lm & 7)

        half8 a0 = *(const half8*)(&alds[ln0][(quad ^ sw) * 8]);
        half8 a1 = *(const half8*)(&alds[ln0][((quad + 4) ^ sw) * 8]);

        int nsafe = nodeD < N_NODES ? nodeD : 0;
        const half8* fp = (const half8*)(fin + (size_t)nsafe * EMB + quad * 8);
        half8 f0 = fp[0], f1 = fp[4];
        half8 g0 = a0 * f0, g1 = a1 * f1;

        float nfv[4][4];
        float sq[4] = {0.f, 0.f, 0.f, 0.f};

        #pragma unroll
        for (int t = 0; t < 4; ++t) {
            int n = t * 16 + lm;
            float bias1 = b1[layer * EMB + n];
            float bias2 = b2[layer * EMB + n];
            half8 w10 = *(const half8*)(&wlds[0][n][(quad ^ sw) * 8]);
            half8 w11 = *(const half8*)(&wlds[0][n][((quad + 4) ^ sw) * 8]);
            half8 w20 = *(const half8*)(&wlds[1][n][(quad ^ sw) * 8]);
            half8 w21 = *(const half8*)(&wlds[1][n][((quad + 4) ^ sw) * 8]);
            floatx4 d1 = {0.f, 0.f, 0.f, 0.f}, d2 = {0.f, 0.f, 0.f, 0.f};
            d1 = __builtin_amdgcn_mfma_f32_16x16x32_f16(a0, w10, d1, 0, 0, 0);
            d1 = __builtin_amdgcn_mfma_f32_16x16x32_f16(a1, w11, d1, 0, 0, 0);
            d2 = __builtin_amdgcn_mfma_f32_16x16x32_f16(g0, w20, d2, 0, 0, 0);
            d2 = __builtin_amdgcn_mfma_f32_16x16x32_f16(g1, w21, d2, 0, 0, 0);
            #pragma unroll
            for (int r = 0; r < 4; ++r) {
                float p1v = d1[r] + bias1;
                p1v = p1v > 0.f ? p1v : 0.2f * p1v;
                float p2v = d2[r] + bias2;
                p2v = p2v > 0.f ? p2v : 0.2f * p2v;
                float nf = p1v + p2v;
                nfv[t][r] = nf;
                sq[r] += nf * nf;
            }
        }

        // fout store — coalesced: contiguous nodes
        #pragma unroll
        for (int t = 0; t < 4; ++t) {
            int dim = t * 16 + lm;
            #pragma unroll
            for (int r = 0; r < 4; ++r) {
                int nodeO = nb + quad * 4 + r;
                if (nodeO < N_NODES)
                    fout[(size_t)nodeO * EMB + dim] = (_Float16)nfv[t][r];
            }
        }

        // per-node L2 norm: reduce sq[r] across the 16 lm-lanes (same quad)
        #pragma unroll
        for (int r = 0; r < 4; ++r) {
            float v = sq[r];
            #pragma unroll
            for (int m = 1; m < 16; m <<= 1) v += __shfl_xor(v, m, 64);
            sq[r] = fmaxf(sqrtf(v), 1e-12f);
        }

        // scatter normalized rows to sampled batch positions
        #pragma unroll
        for (int r = 0; r < 4; ++r) {
            int nodeO = nb + quad * 4 + r;
            if (nodeO >= N_NODES) continue;
            int c = scnt[nodeO]; c = c < SCAP ? c : SCAP;
            float inv = 1.0f / sq[r];
            for (int i2 = 0; i2 < c; ++i2) {
                int smp = smap[nodeO * SCAP + i2];
                float* po = out + (size_t)smp * CONCAT + (layer + 1) * EMB;
                #pragma unroll
                for (int t = 0; t < 4; ++t)
                    po[t * 16 + lm] = nfv[t][r] * inv;
            }
        }
    }
}

// ---------------------------------------------------------------------------
// Last-layer kernel: identical math, but driven by the ACTIVE-node list
// (nodes with >=1 sample, <= 12288 unique). 192 blocks instead of 1954;
// 1.25M edges -> ~120K. No fout store (output only feeds the scatter).
// ---------------------------------------------------------------------------
__global__ __launch_bounds__(256) void layerL_kernel(
    const int* __restrict__ off, const int* __restrict__ endv,
    const unsigned* __restrict__ se,
    const int* __restrict__ nactp, const int* __restrict__ active,
    const _Float16* __restrict__ fin,
    const float* __restrict__ W1, const float* __restrict__ b1,
    const float* __restrict__ W2, const float* __restrict__ b2,
    const int* __restrict__ scnt, const int* __restrict__ smap,
    float* __restrict__ out, int layer) {

    __shared__ _Float16 wlds[2][EMB][EMB];
    __shared__ _Float16 alds[FB_NODES][EMB];

    int tid = threadIdx.x;
    int nact = *nactp;

    // --- stage weights (f32 -> f16, swizzled) ---
    {
        const float* Wsrc0 = W1 + layer * EMB * EMB;
        const float* Wsrc1 = W2 + layer * EMB * EMB;
        #pragma unroll
        for (int m = 0; m < 2; ++m) {
            const float* Ws = m ? Wsrc1 : Wsrc0;
            for (int c = tid; c < 512; c += 256) {
                int n = c >> 3, c16 = c & 7;
                const float* p = Ws + n * EMB + c16 * 8;
                floatx4 wa = *(const floatx4*)p, wb = *(const floatx4*)(p + 4);
                half8 h;
                #pragma unroll
                for (int i = 0; i < 4; ++i) {
                    h[i] = (_Float16)wa[i]; h[4 + i] = (_Float16)wb[i];
                }
                *(half8*)(&wlds[m][n][(c16 ^ (n & 7)) * 8]) = h;
            }
        }
    }

    int wave = tid >> 6, lane = tid & 63;
    int g = lane >> 3;
    int k = lane & 7;
    int base = blockIdx.x * FB_NODES;
    const _Float16* fink = fin + k * 8;

    // --- gather over active nodes ---
    for (int p = 0; p < 2; ++p) {
        int ln = p * 32 + wave * 8 + g;
        int idx = base + ln;
        bool valid = idx < nact;
        int node = valid ? active[idx] : 0;
        int j   = valid ? off[node]  : 0;
        int end = valid ? endv[node] : 0;

        float acc[8] = {0.f, 0.f, 0.f, 0.f, 0.f, 0.f, 0.f, 0.f};
        unsigned ev[8];
        #pragma unroll
        for (int t = 0; t < 8; ++t)
            ev[t] = (j + t < end) ? se[j + t] : 0u;

        while (__any(j < end)) {
            int jn = j + 8;
            half8 h[8];
            #pragma unroll
            for (int t = 0; t < 8; ++t) {
                int c = (int)(ev[t] & 0x1FFFFu);
                h[t] = *(const half8*)(fink + (size_t)c * EMB);
            }
            unsigned evn[8];
            #pragma unroll
            for (int t = 0; t < 8; ++t)
                evn[t] = (jn + t < end) ? se[jn + t] : 0u;
            #pragma unroll
            for (int t = 0; t < 8; ++t) {
                float val = unpack_val(ev[t]);
                #pragma unroll
                for (int i = 0; i < 8; ++i)
                    acc[i] += (float)h[t][i] * val;
                ev[t] = evn[t];
            }
            j = jn;
        }
        half8 o;
        #pragma unroll
        for (int i = 0; i < 8; ++i) o[i] = (_Float16)acc[i];
        *(half8*)(&alds[ln][(k ^ (ln & 7)) * 8]) = o;
    }
    __syncthreads();

    // --- dense phase (active nodes, gathered fin, no fout store) ---
    {
        int lm = lane & 15, quad = lane >> 4;
        int ln0 = wave * 16 + lm;
        int idxD = base + ln0;
        int nodeD = (idxD < nact) ? active[idxD] : -1;
        int sw = lm & 7;

        half8 a0 = *(const half8*)(&alds[ln0][(quad ^ sw) * 8]);
        half8 a1 = *(const half8*)(&alds[ln0][((quad + 4) ^ sw) * 8]);

        int nsafe = nodeD >= 0 ? nodeD : 0;
        const half8* fp = (const half8*)(fin + (size_t)nsafe * EMB + quad * 8);
        half8 f0 = fp[0], f1 = fp[4];
        half8 g0 = a0 * f0, g1 = a1 * f1;

        float nfv[4][4];
        float sq[4] = {0.f, 0.f, 0.f, 0.f};

        #pragma unroll
        for (int t = 0; t < 4; ++t) {
            int n = t * 16 + lm;
            float bias1 = b1[layer * EMB + n];
            float bias2 = b2[layer * EMB + n];
            half8 w10 = *(const half8*)(&wlds[0][n][(quad ^ sw) * 8]);
            half8 w11 = *(const half8*)(&wlds[0][n][((quad + 4) ^ sw) * 8]);
            half8 w20 = *(const half8*)(&wlds[1][n][(quad ^ sw) * 8]);
            half8 w21 = *(const half8*)(&wlds[1][n][((quad + 4) ^ sw) * 8]);
            floatx4 d1 = {0.f, 0.f, 0.f, 0.f}, d2 = {0.f, 0.f, 0.f, 0.f};
            d1 = __builtin_amdgcn_mfma_f32_16x16x32_f16(a0, w10, d1, 0, 0, 0);
            d1 = __builtin_amdgcn_mfma_f32_16x16x32_f16(a1, w11, d1, 0, 0, 0);
            d2 = __builtin_amdgcn_mfma_f32_16x16x32_f16(g0, w20, d2, 0, 0, 0);
            d2 = __builtin_amdgcn_mfma_f32_16x16x32_f16(g1, w21, d2, 0, 0, 0);
            #pragma unroll
            for (int r = 0; r < 4; ++r) {
                float p1v = d1[r] + bias1;
                p1v = p1v > 0.f ? p1v : 0.2f * p1v;
                float p2v = d2[r] + bias2;
                p2v = p2v > 0.f ? p2v : 0.2f * p2v;
                float nf = p1v + p2v;
                nfv[t][r] = nf;
                sq[r] += nf * nf;
            }
        }

        // rows of this wave's tile -> active nodes
        int nodeO[4];
        #pragma unroll
        for (int r = 0; r < 4; ++r)
            nodeO[r] = __shfl(nodeD, quad * 4 + r, 64);

        #pragma unroll
        for (int r = 0; r < 4; ++r) {
            float v = sq[r];
            #pragma unroll
            for (int m = 1; m < 16; m <<= 1) v += __shfl_xor(v, m, 64);
            sq[r] = fmaxf(sqrtf(v), 1e-12f);
        }

        #pragma unroll
        for (int r = 0; r < 4; ++r) {
            if (nodeO[r] < 0) continue;
            int c = scnt[nodeO[r]]; c = c < SCAP ? c : SCAP;
            float inv = 1.0f / sq[r];
            for (int i2 = 0; i2 < c; ++i2) {
                int smp = smap[nodeO[r] * SCAP + i2];
                float* po = out + (size_t)smp * CONCAT + (layer + 1) * EMB;
                #pragma unroll
                for (int t = 0; t < 4; ++t)
                    po[t * 16 + lm] = nfv[t][r] * inv;
            }
        }
    }
}

extern "C" void kernel_launch(void* const* d_in, const int* in_sizes, int n_in,
                              void* d_out, int out_size, void* d_ws, size_t ws_size,
                              hipStream_t stream) {
    const void* user = d_in[0];
    const int* pos  = (const int*)d_in[1];
    const int* neg  = (const int*)d_in[2];
    const int* row  = (const int*)d_in[3];
    const int* col  = (const int*)d_in[4];
    const float* vals = (const float*)d_in[5];
    const float* emb  = (const float*)d_in[6];
    const float* W1   = (const float*)d_in[7];
    const float* b1   = (const float*)d_in[8];
    const float* W2   = (const float*)d_in[9];
    const float* b2   = (const float*)d_in[10];

    // ws layout (all offsets 8B-aligned):
    _Float16* f16a   = (_Float16*)d_ws;                       // 16 MB
    _Float16* f16b   = f16a + (size_t)N_PAD * EMB;            // 16 MB
    int*      off    = (int*)(f16b + (size_t)N_PAD * EMB);    // 125008 ints
    int*      endv   = off + (N_NODES + 8);                   // 125008 ints
    // zero region (contiguous): bcnt | scnt | nact
    int*      bcnt   = endv + (N_NODES + 8);                  // 984 ints
    int*      scnt   = bcnt + 984;                            // 125000 ints
    int*      nact   = scnt + N_NODES;                        // 8 ints
    int*      active = nact + 8;                              // 12288 ints
    int*      smap   = active + 3 * BATCH;                    // 1,000,000 ints
    unsigned long long* sw8 = (unsigned long long*)(smap + N_NODES * SCAP); // 12.5 MB
    unsigned* se     = (unsigned*)(sw8 + (size_t)NB * BCAP);  // 6.25 MB padded CSR

    float* out = (float*)d_out;

    // zero bcnt + scnt + nact in one memset (contiguous)
    hipMemsetAsync(bcnt, 0, (size_t)(984 + N_NODES + 8) * sizeof(int), stream);

    // fused partition + init (+gather0 +sample-map +active-list)
    part_init_kernel<<<NCHUNK + INIT_BLOCKS, 256, 0, stream>>>(
        row, col, vals, emb, user, pos, neg, f16a, out, bcnt, scnt, smap,
        nact, active, sw8);

    bucket_sort_kernel<<<NB, 256, 0, stream>>>(bcnt, sw8, se, off, endv);

    const _Float16* fin = f16a;
    _Float16* fout = f16b;
    for (int l = 0; l < N_LAYERS - 1; ++l) {
        layer_kernel<<<NBLK, 256, 0, stream>>>(
            off, endv, se, fin, fout, W1, b1, W2, b2, scnt, smap, out, l);
        const _Float16* tmp = fout; fout = (_Float16*)fin; fin = (const _Float16*)tmp;
    }
    layerL_kernel<<<NACT_BLK, 256, 0, stream>>>(
        off, endv, se, nact, active, fin, W1, b1, W2, b2, scnt, smap, out,
        N_LAYERS - 1);
}